// Round 13
// baseline (2244.554 us; speedup 1.0000x reference)
//
#include <hip/hip_runtime.h>
#include <hip/hip_bf16.h>
#include <hip/hip_fp16.h>

#define NEGV (-1e30f)

constexpr int Bc = 64;    // batch == wave size
constexpr int Dc = 2048;  // pdf dim
constexpr int Tc = 150;   // time steps
// exp-domain with fp8 E table: E' = e4m3(exp(logp + E_INFL)).
constexpr float E_INFL = 9.5f;
// per-step rescale stored_new = s * K / dref ; K = e^{-3} keeps stored center
// near e^0 (fp16 range +-16 nats). OFF += log(dref) - (E_INFL + 3).
constexpr float K_RESCALE = 0.049787068f;     // e^{-3}
constexpr float OFF_STEP_SUB = E_INFL + 3.0f; // 12.5... wait: -E_INFL - log K = -9.5 + 3
// NOTE: OFF_new = OFF_old + log(dref) - E_INFL - log(K) = OFF + log(dref) - 9.5 + 3
constexpr float OFF_DELTA_SUB = 6.5f;
constexpr float STORE_CAP = 60000.0f;         // fp16 overflow guard (never hit at eq.)
constexpr float OFF_INIT = -10.0f;            // stored_init = exp(init_logp + 10) ~ e^0

// ---- OCP e4m3 software encode (setup only) ----
__device__ __forceinline__ unsigned enc_e4m3(float x) {
    x = fminf(x, 448.0f);
    if (x < 0.0009765625f) return 0u;            // < half min denorm -> 0
    if (x < 0.015625f) {                          // denormal: m * 2^-9
        unsigned m = (unsigned)(x * 512.0f + 0.5f);
        return m > 7u ? 8u : m;                   // m==8 -> e=1,m=0 (2^-6)
    }
    unsigned bits = __float_as_uint(x);
    unsigned e32  = (bits >> 23) & 0xFF;          // 121..135
    unsigned m3   = ((bits & 0x7FFFFF) + 0x80000) >> 20;  // round
    unsigned e    = e32 - 120;
    if (m3 == 8u) { m3 = 0u; e += 1u; }
    if (e > 15u || (e == 15u && m3 == 7u)) return 0x7Eu;  // sat 448
    return (e << 3) | m3;
}

// ---- OCP e4m3 software decode (hot loop, branchless ~6 VALU) ----
__device__ __forceinline__ float dec_e4m3(unsigned u) {
    unsigned e = (u >> 3) & 0xFu, m = u & 7u;
    float norm = __uint_as_float(((e + 120u) << 23) | (m << 20));
    float den  = (float)m * 0.001953125f;         // 2^-9
    return e ? norm : den;
}

// ---- transpose input [T][B][D] f32 -> E'=e4m3(exp(logp+E_INFL)) [T][D][B] ----
__global__ void transpose_kernel(const float* __restrict__ in,
                                 unsigned char* __restrict__ out) {
    __shared__ float tile[64][65];
    const int t  = blockIdx.y;
    const int d0 = blockIdx.x * 64;
    const int lane = threadIdx.x & 63;
    const int w    = threadIdx.x >> 6;  // 0..3
    const float* inp = in + (size_t)t * Bc * Dc;
    #pragma unroll
    for (int b = w; b < 64; b += 4)
        tile[b][lane] = inp[(size_t)b * Dc + d0 + lane];
    __syncthreads();
    unsigned char* outp = out + (size_t)t * Dc * Bc;
    #pragma unroll
    for (int d = w; d < 64; d += 4)
        outp[(size_t)(d0 + d) * Bc + lane] =
            (unsigned char)enc_e4m3(__expf(tile[lane][d] + E_INFL));
}

// ---- EA[s][b] = exp(init_logp[s] - OFF_INIT); off[b] = OFF_INIT ----
__global__ void init_alpha_kernel(const float* __restrict__ init_logp,
                                  __half* __restrict__ alpha_h,
                                  float* __restrict__ off, int S) {
    int idx  = blockIdx.x * blockDim.x + threadIdx.x;
    int wave = idx >> 6;
    int lane = threadIdx.x & 63;
    if (wave < S) {
        float v = __expf(init_logp[wave] - OFF_INIT);
        alpha_h[(size_t)wave * Bc + lane] = __float2half(fminf(v, STORE_CAP));
    }
    if (idx < Bc) off[idx] = OFF_INIT;
}

// ---- histogram of to_state ----
__global__ void hist_kernel(const int* __restrict__ to, int* __restrict__ count, int A) {
    int i = blockIdx.x * blockDim.x + threadIdx.x;
    if (i < A) atomicAdd(&count[to[i]], 1);
}

// ---- single-block exclusive scan -> row_ptr, cursor ----
__global__ void scan_kernel(const int* __restrict__ count, int* __restrict__ row_ptr,
                            int* __restrict__ cursor, int S) {
    __shared__ int lds[1024];
    const int tid = threadIdx.x;
    const int n = 1024;
    const int chunk = (S + n - 1) / n;
    const int lo = tid * chunk;
    const int hi = min(lo + chunk, S);
    int local = 0;
    for (int j = lo; j < hi; ++j) local += count[j];
    lds[tid] = local;
    __syncthreads();
    for (int off = 1; off < 1024; off <<= 1) {
        int add = (tid >= off) ? lds[tid - off] : 0;
        __syncthreads();
        lds[tid] += add;
        __syncthreads();
    }
    int excl = (tid > 0) ? lds[tid - 1] : 0;
    for (int j = lo; j < hi; ++j) {
        int c = count[j];
        row_ptr[j] = excl;
        cursor[j]  = excl;
        excl += c;
    }
    if (tid == n - 1) row_ptr[S] = lds[n - 1];
}

// ---- scatter arcs sorted by to_state, packed 8B: {f:u32, pdf:u16, exp(w):fp16} ----
__global__ void scatter_kernel(const int* __restrict__ to, const int* __restrict__ from,
                               const int* __restrict__ pdf, const float* __restrict__ w,
                               int* __restrict__ cursor, uint2* __restrict__ a_pack, int A) {
    int i = blockIdx.x * blockDim.x + threadIdx.x;
    if (i >= A) return;
    int t = to[i];
    int p = atomicAdd(&cursor[t], 1);
    unsigned short wb = __half_as_ushort(__float2half(__expf(w[i])));
    a_pack[p] = make_uint2((unsigned)from[i],
                           ((unsigned)pdf[i] & 0xffffu) | ((unsigned)wb << 16));
}

// ---- one forward step, exp domain, fp8 E gather (64B lines) ----
// wave = state, lane = batch. XCD-contiguous swizzle for L2 locality.
// TR: E' fp8 [D][B]. else: raw f32 logp [B][D] (fallback, exp inline).
template <bool TR>
__global__ void step_kernel(const __half* __restrict__ alpha_old,  // [S][B] EA fp16
                            __half* __restrict__ alpha_new,        // [S][B] EA fp16
                            const float* __restrict__ off_old,     // [B]
                            float* __restrict__ off_new,           // [B]
                            const void* __restrict__ logp_t,
                            const int* __restrict__ row_ptr,
                            const uint2* __restrict__ arcs, int S) {
    const int nb  = gridDim.x;
    const int cpx = nb >> 3;
    const int bid = blockIdx.x;
    const int swz = (nb % 8 == 0) ? ((bid & 7) * cpx + (bid >> 3)) : bid;
    const int wave = (swz * blockDim.x + threadIdx.x) >> 6;
    const int lane = threadIdx.x & 63;
    if (wave >= S) return;
    const int lo = __builtin_amdgcn_readfirstlane(row_ptr[wave]);
    const int hi = __builtin_amdgcn_readfirstlane(row_ptr[wave + 1]);
    const unsigned char* lpb = (const unsigned char*)logp_t;
    const float* lpf = (const float*)logp_t;

    // multiplicative re-center reference from states 0..3 (self-correcting)
    const float r0 = __half2float(alpha_old[0 * Bc + lane]);
    const float r1 = __half2float(alpha_old[1 * Bc + lane]);
    const float r2 = __half2float(alpha_old[2 * Bc + lane]);
    const float r3 = __half2float(alpha_old[3 * Bc + lane]);
    const float dref = fmaxf(fmaxf(fmaxf(r0, r1), fmaxf(r2, r3)), 1e-20f);
    const float scale = K_RESCALE / dref;

    float s0 = 0.0f, s1 = 0.0f, s2 = 0.0f, s3 = 0.0f;
    int i = lo;
    for (; i + 3 < hi; i += 4) {
        const uint2 A0 = arcs[i],     A1 = arcs[i + 1];
        const uint2 A2 = arcs[i + 2], A3 = arcs[i + 3];
        const float w0 = __half2float(__ushort_as_half((unsigned short)(A0.y >> 16)));
        const float w1 = __half2float(__ushort_as_half((unsigned short)(A1.y >> 16)));
        const float w2 = __half2float(__ushort_as_half((unsigned short)(A2.y >> 16)));
        const float w3 = __half2float(__ushort_as_half((unsigned short)(A3.y >> 16)));
        const float e0 = TR ? dec_e4m3(lpb[(size_t)(A0.y & 0xffffu) * Bc + lane])
                            : __expf(lpf[(size_t)lane * Dc + (A0.y & 0xffffu)] + E_INFL);
        const float e1 = TR ? dec_e4m3(lpb[(size_t)(A1.y & 0xffffu) * Bc + lane])
                            : __expf(lpf[(size_t)lane * Dc + (A1.y & 0xffffu)] + E_INFL);
        const float e2 = TR ? dec_e4m3(lpb[(size_t)(A2.y & 0xffffu) * Bc + lane])
                            : __expf(lpf[(size_t)lane * Dc + (A2.y & 0xffffu)] + E_INFL);
        const float e3 = TR ? dec_e4m3(lpb[(size_t)(A3.y & 0xffffu) * Bc + lane])
                            : __expf(lpf[(size_t)lane * Dc + (A3.y & 0xffffu)] + E_INFL);
        const float a0 = __half2float(alpha_old[(size_t)A0.x * Bc + lane]);
        const float a1 = __half2float(alpha_old[(size_t)A1.x * Bc + lane]);
        const float a2 = __half2float(alpha_old[(size_t)A2.x * Bc + lane]);
        const float a3 = __half2float(alpha_old[(size_t)A3.x * Bc + lane]);
        s0 = fmaf(a0 * w0, e0, s0);
        s1 = fmaf(a1 * w1, e1, s1);
        s2 = fmaf(a2 * w2, e2, s2);
        s3 = fmaf(a3 * w3, e3, s3);
    }
    for (; i < hi; ++i) {
        const uint2 A0 = arcs[i];
        const float w0 = __half2float(__ushort_as_half((unsigned short)(A0.y >> 16)));
        const float e0 = TR ? dec_e4m3(lpb[(size_t)(A0.y & 0xffffu) * Bc + lane])
                            : __expf(lpf[(size_t)lane * Dc + (A0.y & 0xffffu)] + E_INFL);
        const float a0 = __half2float(alpha_old[(size_t)A0.x * Bc + lane]);
        s0 = fmaf(a0 * w0, e0, s0);
    }
    const float s = (s0 + s1) + (s2 + s3);
    alpha_new[(size_t)wave * Bc + lane] = __float2half(fminf(s * scale, STORE_CAP));
    if (wave == 0) off_new[lane] = off_old[lane] + (__logf(dref) - OFF_DELTA_SUB);
}

// ---- final: per-batch logsumexp(log(EA) + final_logp) + OFF[b], atomicAdd ----
__global__ void final_reduce_kernel(const __half* __restrict__ alpha,
                                    const float* __restrict__ off,
                                    const float* __restrict__ final_logp,
                                    float* __restrict__ out, int S) {
    const int b = blockIdx.x;     // 0..B-1
    const int tid = threadIdx.x;  // 256
    float m = NEGV, sum = 0.0f;
    for (int s = tid; s < S; s += 256) {
        float ea = __half2float(alpha[(size_t)s * Bc + b]);
        float v = __logf(ea + 1e-35f) + final_logp[s];
        float nm = fmaxf(m, v);
        sum = sum * __expf(m - nm) + __expf(v - nm);
        m = nm;
    }
    __shared__ float mArr[256], sArr[256];
    mArr[tid] = m; sArr[tid] = sum;
    __syncthreads();
    for (int o = 128; o > 0; o >>= 1) {
        if (tid < o) {
            float m2 = mArr[tid + o], s2 = sArr[tid + o];
            float nm = fmaxf(mArr[tid], m2);
            sArr[tid] = sArr[tid] * __expf(mArr[tid] - nm) + s2 * __expf(m2 - nm);
            mArr[tid] = nm;
        }
        __syncthreads();
    }
    if (tid == 0) {
        float per = fmaxf(mArr[0], NEGV) + logf(sArr[0] + 1e-30f) + off[b];
        atomicAdd(out, per);
    }
}

extern "C" void kernel_launch(void* const* d_in, const int* in_sizes, int n_in,
                              void* d_out, int out_size, void* d_ws, size_t ws_size,
                              hipStream_t stream) {
    const float* input      = (const float*)d_in[0];
    const float* arc_logw   = (const float*)d_in[1];
    const float* init_logp  = (const float*)d_in[2];
    const float* final_logp = (const float*)d_in[3];
    const int*   from_state = (const int*)d_in[4];
    const int*   to_state   = (const int*)d_in[5];
    const int*   pdf_id     = (const int*)d_in[6];
    const int S = in_sizes[2];
    const int A = in_sizes[4];

    char* ws = (char*)d_ws;
    size_t off = 0;
    auto alloc = [&](size_t bytes) -> char* {
        char* p = ws + off;
        off += (bytes + 255) & ~(size_t)255;
        return p;
    };

    const size_t need_small =
        2 * (((size_t)S * Bc * 2 + 255) & ~(size_t)255) +   // alphaA/B fp16
        (((size_t)A * 8 + 255) & ~(size_t)255) +            // packed arcs
        3 * (((size_t)(S + 1) * 4 + 255) & ~(size_t)255) +  // row_ptr/cursor/count
        2 * 256;                                            // offA/B
    const size_t need_T = (size_t)Tc * Dc * Bc * 1 + 256;   // fp8 E table 19.7 MB
    const bool do_transpose = (ws_size >= need_small + need_T);

    unsigned char* logpE = nullptr;
    if (do_transpose) logpE = (unsigned char*)alloc(need_T);
    __half* alphaA = (__half*)alloc((size_t)S * Bc * 2);
    __half* alphaB = (__half*)alloc((size_t)S * Bc * 2);
    float* offA    = (float*)alloc(Bc * 4);
    float* offB    = (float*)alloc(Bc * 4);
    int*   row_ptr = (int*)alloc((size_t)(S + 1) * 4);
    int*   cursor  = (int*)alloc((size_t)(S + 1) * 4);
    int*   count   = (int*)alloc((size_t)(S + 1) * 4);
    uint2* a_pack  = (uint2*)alloc((size_t)A * 8);

    hipMemsetAsync(count, 0, (size_t)S * 4, stream);
    hipMemsetAsync(d_out, 0, sizeof(float), stream);

    if (do_transpose) {
        dim3 tgrid(Dc / 64, Tc);
        transpose_kernel<<<tgrid, 256, 0, stream>>>(input, logpE);
    }
    init_alpha_kernel<<<(S * Bc + 255) / 256, 256, 0, stream>>>(init_logp, alphaA,
                                                                offA, S);
    hist_kernel<<<(A + 255) / 256, 256, 0, stream>>>(to_state, count, A);
    scan_kernel<<<1, 1024, 0, stream>>>(count, row_ptr, cursor, S);
    scatter_kernel<<<(A + 255) / 256, 256, 0, stream>>>(to_state, from_state, pdf_id,
                                                        arc_logw, cursor, a_pack, A);

    __half* curA = alphaA;  __half* nxtA = alphaB;
    float*  curO = offA;    float*  nxtO = offB;
    int step_blocks = (S + 7) / 8;                 // 8 states / 512-thr block
    step_blocks = (step_blocks + 7) & ~7;          // 2504, mult of 8 for swizzle
    for (int t = 0; t < Tc; ++t) {
        if (do_transpose) {
            step_kernel<true><<<step_blocks, 512, 0, stream>>>(
                curA, nxtA, curO, nxtO, logpE + (size_t)t * Dc * Bc, row_ptr, a_pack, S);
        } else {
            step_kernel<false><<<step_blocks, 512, 0, stream>>>(
                curA, nxtA, curO, nxtO, input + (size_t)t * Bc * Dc, row_ptr, a_pack, S);
        }
        __half* ta = curA; curA = nxtA; nxtA = ta;
        float*  to_ = curO; curO = nxtO; nxtO = to_;
    }
    final_reduce_kernel<<<Bc, 256, 0, stream>>>(curA, curO, final_logp, (float*)d_out, S);
}

// Round 14
// 2016.545 us; speedup vs baseline: 1.1131x; 1.1131x over previous
//
#include <hip/hip_runtime.h>
#include <hip/hip_bf16.h>
#include <hip/hip_fp16.h>

#define NEGV (-1e30f)

constexpr int Bc = 64;    // batch == wave size
constexpr int Dc = 2048;  // pdf dim
constexpr int Tc = 150;   // time steps
// exp-domain re-centering: stored EA ~ O(1..100); per-step rescale by
// e^{+5}/max(EA[0..3]) counters the ~-5 nat/step drift (self-correcting).
constexpr float EXP_NEG_DRIFT = 148.41316f;   // e^{5}
constexpr float STORE_CAP = 60000.0f;         // fp16 max 65504, keep headroom
constexpr float OFF_INIT = -10.0f;            // stored_init = exp(init_logp + 10)

// ---- transpose input [T][B][D] f32 -> E=exp(logp) [T][D][B] fp16 ----
__global__ void transpose_kernel(const float* __restrict__ in, __half* __restrict__ out) {
    __shared__ float tile[64][65];
    const int t  = blockIdx.y;
    const int d0 = blockIdx.x * 64;
    const int lane = threadIdx.x & 63;
    const int w    = threadIdx.x >> 6;  // 0..3
    const float* inp = in + (size_t)t * Bc * Dc;
    #pragma unroll
    for (int b = w; b < 64; b += 4)
        tile[b][lane] = inp[(size_t)b * Dc + d0 + lane];
    __syncthreads();
    __half* outp = out + (size_t)t * Dc * Bc;
    #pragma unroll
    for (int d = w; d < 64; d += 4)
        outp[(size_t)(d0 + d) * Bc + lane] = __float2half(__expf(tile[lane][d]));
}

// ---- EA[s][b] = exp(init_logp[s] - OFF_INIT); off[b] = OFF_INIT ----
__global__ void init_alpha_kernel(const float* __restrict__ init_logp,
                                  __half* __restrict__ alpha_h,
                                  float* __restrict__ off, int S) {
    int idx  = blockIdx.x * blockDim.x + threadIdx.x;
    int wave = idx >> 6;
    int lane = threadIdx.x & 63;
    if (wave < S) {
        float v = __expf(init_logp[wave] - OFF_INIT);
        alpha_h[(size_t)wave * Bc + lane] = __float2half(fminf(v, STORE_CAP));
    }
    if (idx < Bc) off[idx] = OFF_INIT;
}

// ---- histogram of to_state ----
__global__ void hist_kernel(const int* __restrict__ to, int* __restrict__ count, int A) {
    int i = blockIdx.x * blockDim.x + threadIdx.x;
    if (i < A) atomicAdd(&count[to[i]], 1);
}

// ---- single-block exclusive scan -> row_ptr, cursor ----
__global__ void scan_kernel(const int* __restrict__ count, int* __restrict__ row_ptr,
                            int* __restrict__ cursor, int S) {
    __shared__ int lds[1024];
    const int tid = threadIdx.x;
    const int n = 1024;
    const int chunk = (S + n - 1) / n;
    const int lo = tid * chunk;
    const int hi = min(lo + chunk, S);
    int local = 0;
    for (int j = lo; j < hi; ++j) local += count[j];
    lds[tid] = local;
    __syncthreads();
    for (int off = 1; off < 1024; off <<= 1) {
        int add = (tid >= off) ? lds[tid - off] : 0;
        __syncthreads();
        lds[tid] += add;
        __syncthreads();
    }
    int excl = (tid > 0) ? lds[tid - 1] : 0;
    for (int j = lo; j < hi; ++j) {
        int c = count[j];
        row_ptr[j] = excl;
        cursor[j]  = excl;
        excl += c;
    }
    if (tid == n - 1) row_ptr[S] = lds[n - 1];
}

// ---- scatter arcs sorted by to_state, packed 8B: {f:u32, pdf:u16, exp(w):fp16} ----
__global__ void scatter_kernel(const int* __restrict__ to, const int* __restrict__ from,
                               const int* __restrict__ pdf, const float* __restrict__ w,
                               int* __restrict__ cursor, uint2* __restrict__ a_pack, int A) {
    int i = blockIdx.x * blockDim.x + threadIdx.x;
    if (i >= A) return;
    int t = to[i];
    int p = atomicAdd(&cursor[t], 1);
    unsigned short wb = __half_as_ushort(__float2half(__expf(w[i])));
    a_pack[p] = make_uint2((unsigned)from[i],
                           ((unsigned)pdf[i] & 0xffffu) | ((unsigned)wb << 16));
}

// ---- one forward step, EXP DOMAIN: s = sum EA[f]*ew*E[p]; no transcendentals ----
// wave = state, lane = batch. XCD-contiguous swizzle for L2 locality.
// TR: E is fp16 [D][B]. else: raw f32 logp [B][D] (fallback, exp inline).
template <bool TR>
__global__ void step_kernel(const __half* __restrict__ alpha_old,  // [S][B] EA fp16
                            __half* __restrict__ alpha_new,        // [S][B] EA fp16
                            const float* __restrict__ off_old,     // [B]
                            float* __restrict__ off_new,           // [B]
                            const void* __restrict__ logp_t,
                            const int* __restrict__ row_ptr,
                            const uint2* __restrict__ arcs, int S) {
    const int nb  = gridDim.x;
    const int cpx = nb >> 3;
    const int bid = blockIdx.x;
    const int swz = (nb % 8 == 0) ? ((bid & 7) * cpx + (bid >> 3)) : bid;
    const int wave = (swz * blockDim.x + threadIdx.x) >> 6;
    const int lane = threadIdx.x & 63;
    if (wave >= S) return;
    const int lo = __builtin_amdgcn_readfirstlane(row_ptr[wave]);
    const int hi = __builtin_amdgcn_readfirstlane(row_ptr[wave + 1]);
    const __half* lph = (const __half*)logp_t;
    const float*  lpf = (const float*)logp_t;

    // multiplicative re-center reference from states 0..3 (self-correcting)
    const float r0 = __half2float(alpha_old[0 * Bc + lane]);
    const float r1 = __half2float(alpha_old[1 * Bc + lane]);
    const float r2 = __half2float(alpha_old[2 * Bc + lane]);
    const float r3 = __half2float(alpha_old[3 * Bc + lane]);
    const float dref = fmaxf(fmaxf(fmaxf(r0, r1), fmaxf(r2, r3)), 1e-20f);
    const float scale = EXP_NEG_DRIFT / dref;   // = exp(-delta)

    float s0 = 0.0f, s1 = 0.0f, s2 = 0.0f, s3 = 0.0f;
    int i = lo;
    for (; i + 3 < hi; i += 4) {
        const uint2 A0 = arcs[i],     A1 = arcs[i + 1];
        const uint2 A2 = arcs[i + 2], A3 = arcs[i + 3];
        const float w0 = __half2float(__ushort_as_half((unsigned short)(A0.y >> 16)));
        const float w1 = __half2float(__ushort_as_half((unsigned short)(A1.y >> 16)));
        const float w2 = __half2float(__ushort_as_half((unsigned short)(A2.y >> 16)));
        const float w3 = __half2float(__ushort_as_half((unsigned short)(A3.y >> 16)));
        const float e0 = TR ? __half2float(lph[(size_t)(A0.y & 0xffffu) * Bc + lane])
                            : __expf(lpf[(size_t)lane * Dc + (A0.y & 0xffffu)]);
        const float e1 = TR ? __half2float(lph[(size_t)(A1.y & 0xffffu) * Bc + lane])
                            : __expf(lpf[(size_t)lane * Dc + (A1.y & 0xffffu)]);
        const float e2 = TR ? __half2float(lph[(size_t)(A2.y & 0xffffu) * Bc + lane])
                            : __expf(lpf[(size_t)lane * Dc + (A2.y & 0xffffu)]);
        const float e3 = TR ? __half2float(lph[(size_t)(A3.y & 0xffffu) * Bc + lane])
                            : __expf(lpf[(size_t)lane * Dc + (A3.y & 0xffffu)]);
        const float a0 = __half2float(alpha_old[(size_t)A0.x * Bc + lane]);
        const float a1 = __half2float(alpha_old[(size_t)A1.x * Bc + lane]);
        const float a2 = __half2float(alpha_old[(size_t)A2.x * Bc + lane]);
        const float a3 = __half2float(alpha_old[(size_t)A3.x * Bc + lane]);
        s0 = fmaf(a0 * w0, e0, s0);
        s1 = fmaf(a1 * w1, e1, s1);
        s2 = fmaf(a2 * w2, e2, s2);
        s3 = fmaf(a3 * w3, e3, s3);
    }
    for (; i < hi; ++i) {
        const uint2 A0 = arcs[i];
        const float w0 = __half2float(__ushort_as_half((unsigned short)(A0.y >> 16)));
        const float e0 = TR ? __half2float(lph[(size_t)(A0.y & 0xffffu) * Bc + lane])
                            : __expf(lpf[(size_t)lane * Dc + (A0.y & 0xffffu)]);
        const float a0 = __half2float(alpha_old[(size_t)A0.x * Bc + lane]);
        s0 = fmaf(a0 * w0, e0, s0);
    }
    const float s = (s0 + s1) + (s2 + s3);
    alpha_new[(size_t)wave * Bc + lane] = __float2half(fminf(s * scale, STORE_CAP));
    if (wave == 0) off_new[lane] = off_old[lane] + (__logf(dref) - 5.0f);
}

// ---- final: per-batch logsumexp(log(EA) + final_logp) + OFF[b], atomicAdd ----
__global__ void final_reduce_kernel(const __half* __restrict__ alpha,
                                    const float* __restrict__ off,
                                    const float* __restrict__ final_logp,
                                    float* __restrict__ out, int S) {
    const int b = blockIdx.x;     // 0..B-1
    const int tid = threadIdx.x;  // 256
    float m = NEGV, sum = 0.0f;
    for (int s = tid; s < S; s += 256) {
        float ea = __half2float(alpha[(size_t)s * Bc + b]);
        float v = __logf(ea + 1e-35f) + final_logp[s];
        float nm = fmaxf(m, v);
        sum = sum * __expf(m - nm) + __expf(v - nm);
        m = nm;
    }
    __shared__ float mArr[256], sArr[256];
    mArr[tid] = m; sArr[tid] = sum;
    __syncthreads();
    for (int o = 128; o > 0; o >>= 1) {
        if (tid < o) {
            float m2 = mArr[tid + o], s2 = sArr[tid + o];
            float nm = fmaxf(mArr[tid], m2);
            sArr[tid] = sArr[tid] * __expf(mArr[tid] - nm) + s2 * __expf(m2 - nm);
            mArr[tid] = nm;
        }
        __syncthreads();
    }
    if (tid == 0) {
        float per = fmaxf(mArr[0], NEGV) + logf(sArr[0] + 1e-30f) + off[b];
        atomicAdd(out, per);
    }
}

extern "C" void kernel_launch(void* const* d_in, const int* in_sizes, int n_in,
                              void* d_out, int out_size, void* d_ws, size_t ws_size,
                              hipStream_t stream) {
    const float* input      = (const float*)d_in[0];
    const float* arc_logw   = (const float*)d_in[1];
    const float* init_logp  = (const float*)d_in[2];
    const float* final_logp = (const float*)d_in[3];
    const int*   from_state = (const int*)d_in[4];
    const int*   to_state   = (const int*)d_in[5];
    const int*   pdf_id     = (const int*)d_in[6];
    const int S = in_sizes[2];
    const int A = in_sizes[4];

    char* ws = (char*)d_ws;
    size_t off = 0;
    auto alloc = [&](size_t bytes) -> char* {
        char* p = ws + off;
        off += (bytes + 255) & ~(size_t)255;
        return p;
    };

    const size_t need_small =
        2 * (((size_t)S * Bc * 2 + 255) & ~(size_t)255) +   // alphaA/B fp16
        (((size_t)A * 8 + 255) & ~(size_t)255) +            // packed arcs
        3 * (((size_t)(S + 1) * 4 + 255) & ~(size_t)255) +  // row_ptr/cursor/count
        2 * 256;                                            // offA/B
    const size_t need_T = (size_t)Tc * Dc * Bc * 2 + 256;
    const bool do_transpose = (ws_size >= need_small + need_T);

    __half* logpT = nullptr;
    if (do_transpose) logpT = (__half*)alloc(need_T);
    __half* alphaA = (__half*)alloc((size_t)S * Bc * 2);
    __half* alphaB = (__half*)alloc((size_t)S * Bc * 2);
    float* offA    = (float*)alloc(Bc * 4);
    float* offB    = (float*)alloc(Bc * 4);
    int*   row_ptr = (int*)alloc((size_t)(S + 1) * 4);
    int*   cursor  = (int*)alloc((size_t)(S + 1) * 4);
    int*   count   = (int*)alloc((size_t)(S + 1) * 4);
    uint2* a_pack  = (uint2*)alloc((size_t)A * 8);

    hipMemsetAsync(count, 0, (size_t)S * 4, stream);
    hipMemsetAsync(d_out, 0, sizeof(float), stream);

    if (do_transpose) {
        dim3 tgrid(Dc / 64, Tc);
        transpose_kernel<<<tgrid, 256, 0, stream>>>(input, logpT);
    }
    init_alpha_kernel<<<(S * Bc + 255) / 256, 256, 0, stream>>>(init_logp, alphaA,
                                                                offA, S);
    hist_kernel<<<(A + 255) / 256, 256, 0, stream>>>(to_state, count, A);
    scan_kernel<<<1, 1024, 0, stream>>>(count, row_ptr, cursor, S);
    scatter_kernel<<<(A + 255) / 256, 256, 0, stream>>>(to_state, from_state, pdf_id,
                                                        arc_logw, cursor, a_pack, A);

    __half* curA = alphaA;  __half* nxtA = alphaB;
    float*  curO = offA;    float*  nxtO = offB;
    // 512-thread blocks: 8 states/block -> ~2500 blocks; pad to mult of 8 for
    // the bijective XCD swizzle.
    int step_blocks = (S + 7) / 8;
    step_blocks = (step_blocks + 7) & ~7;          // 2504 for S=20000
    for (int t = 0; t < Tc; ++t) {
        if (do_transpose) {
            step_kernel<true><<<step_blocks, 512, 0, stream>>>(
                curA, nxtA, curO, nxtO, logpT + (size_t)t * Dc * Bc, row_ptr, a_pack, S);
        } else {
            step_kernel<false><<<step_blocks, 512, 0, stream>>>(
                curA, nxtA, curO, nxtO, input + (size_t)t * Bc * Dc, row_ptr, a_pack, S);
        }
        __half* ta = curA; curA = nxtA; nxtA = ta;
        float*  to_ = curO; curO = nxtO; nxtO = to_;
    }
    final_reduce_kernel<<<Bc, 256, 0, stream>>>(curA, curO, final_logp, (float*)d_out, S);
}